// Round 1
// baseline (6697.330 us; speedup 1.0000x reference)
//
#include <hip/hip_runtime.h>
#include <cstdint>
#include <cstddef>

#define H 1024
#define SEQ 512
#define THREEH 3072
#define VOCABN 32000
#define NBLK 64
#define HPB 16      // h-indices per block = H / NBLK
#define RPB 48      // rows per block = 3*HPB
#define RPW 12      // rows per wave = RPB / 4

__device__ __forceinline__ float wave_sum(float v) {
    v += __shfl_xor(v, 32);
    v += __shfl_xor(v, 16);
    v += __shfl_xor(v, 8);
    v += __shfl_xor(v, 4);
    v += __shfl_xor(v, 2);
    v += __shfl_xor(v, 1);
    return v;
}

// Persistent recurrent kernel: 64 blocks, each owns 16 h-indices (48 rows of
// Whh held in VGPRs: 12 rows/wave x 16 floats/lane = 48 float4 regs/thread).
// Cross-block h exchange via agent-scope relaxed atomics (sc0 sc1 -> LLC),
// flag-array barrier with monotonic step counter.
__global__ __launch_bounds__(256, 1) void rnn_persistent(
    const float* __restrict__ eWhh, const float* __restrict__ ebhh,
    const float* __restrict__ dWhh, const float* __restrict__ dbhh,
    const float* __restrict__ gxe, const float* __restrict__ gxd,
    float* __restrict__ hbuf,      // [2][H] double buffer (enc)
    float* __restrict__ dec_hs,    // [SEQ][H]
    unsigned* __restrict__ flags)  // [NBLK*16], zeroed before launch
{
    const int tid = threadIdx.x;
    const int blk = blockIdx.x;
    const int wave = tid >> 6;
    const int lane = tid & 63;
    const int i0 = blk * HPB;

    __shared__ float hs[H];
    __shared__ float ghs[RPB];
    __shared__ float bhs[RPB];

    float4 wreg[RPW][4];

    auto load_w = [&](const float* __restrict__ W, const float* __restrict__ bhh) {
#pragma unroll
        for (int j = 0; j < RPW; ++j) {
            int lr = wave * RPW + j;
            int g = lr / HPB, jj = lr % HPB;
            const float* base = W + (size_t)(g * H + i0 + jj) * H + lane * 4;
#pragma unroll
            for (int m = 0; m < 4; ++m)
                wreg[j][m] = *(const float4*)(base + 256 * m);
        }
        if (tid < RPB) {
            int g = tid / HPB, jj = tid % HPB;
            bhs[tid] = bhh[g * H + i0 + jj];
        }
        __syncthreads();
    };

    load_w(eWhh, ebhh);

    for (unsigned step = 0; step < 2 * SEQ; ++step) {
        const bool dec = step >= SEQ;
        const int t = dec ? (int)(step - SEQ) : (int)step;
        if (dec && t == 0) load_w(dWhh, dbhh);

        const float* gx = dec ? gxd : gxe;
        const float* hprev;
        float* hout;
        if (!dec) {
            hprev = (t == 0) ? nullptr : hbuf + (t & 1) * H;
            hout = hbuf + ((t + 1) & 1) * H;
        } else {
            hprev = (t == 0) ? hbuf : dec_hs + (size_t)(t - 1) * H;
            hout = dec_hs + (size_t)t * H;
        }

        // stage h into LDS (fresh from LLC via sc0 sc1 loads)
        if (hprev) {
            for (int k = tid; k < H; k += 256)
                hs[k] = __hip_atomic_load(hprev + k, __ATOMIC_RELAXED,
                                          __HIP_MEMORY_SCOPE_AGENT);
        } else {
            for (int k = tid; k < H; k += 256) hs[k] = 0.f;
        }

        // prefetch gx for gate threads (used after the matvec)
        float gxr = 0.f, gxz = 0.f, gxn = 0.f;
        if (tid < HPB) {
            const float* g = gx + (size_t)t * THREEH;
            gxr = g[i0 + tid];
            gxz = g[H + i0 + tid];
            gxn = g[2 * H + i0 + tid];
        }
        __syncthreads();

        float4 h4[4];
#pragma unroll
        for (int m = 0; m < 4; ++m)
            h4[m] = *(const float4*)&hs[lane * 4 + 256 * m];

#pragma unroll
        for (int j = 0; j < RPW; ++j) {
            float acc = 0.f;
#pragma unroll
            for (int m = 0; m < 4; ++m) {
                float4 w = wreg[j][m], h = h4[m];
                acc += w.x * h.x + w.y * h.y + w.z * h.z + w.w * h.w;
            }
            acc = wave_sum(acc);
            if (lane == 0) ghs[wave * RPW + j] = acc;
        }
        __syncthreads();

        if (tid < HPB) {
            float hv = hs[i0 + tid];
            float ghr = ghs[tid] + bhs[tid];
            float ghz = ghs[HPB + tid] + bhs[HPB + tid];
            float ghn = ghs[2 * HPB + tid] + bhs[2 * HPB + tid];
            float r = 1.f / (1.f + expf(-(gxr + ghr)));
            float z = 1.f / (1.f + expf(-(gxz + ghz)));
            float n = tanhf(gxn + r * ghn);
            float hnew = (1.f - z) * n + z * hv;
            __hip_atomic_store(hout + i0 + tid, hnew, __ATOMIC_RELAXED,
                               __HIP_MEMORY_SCOPE_AGENT);
        }
        // syncthreads drains wave0's vmcnt -> h stores are at LLC before flag
        __syncthreads();
        if (tid == 0)
            __hip_atomic_store(flags + (size_t)blk * 16, step + 1,
                               __ATOMIC_RELAXED, __HIP_MEMORY_SCOPE_AGENT);
        if (tid < 64) {
            const unsigned target = step + 1;
            while (true) {
                unsigned f = __hip_atomic_load(flags + (size_t)tid * 16,
                                               __ATOMIC_RELAXED,
                                               __HIP_MEMORY_SCOPE_AGENT);
                if (__all((int)(f >= target))) break;
            }
        }
        __syncthreads();
    }
}

// Tiled fp32 GEMM, C[m][n] = dot(Arow(m), W[n]) + bias[n].
// mode 0: Arow = Abase[inputs[m]]   (encoder embedding gather)
// mode 1: Arow = Abase[m==0 ? 0 : targets[m-1]] (decoder teacher forcing)
// mode 2: Arow = Abase[m]           (projection from dec_hs)
__global__ __launch_bounds__(256, 2) void gemm_nt(
    const float* __restrict__ Abase,
    const int* __restrict__ toks0,
    const int* __restrict__ toks1,
    const int mode,
    const float* __restrict__ W,
    const float* __restrict__ bias,
    float* __restrict__ C, const int N)
{
    constexpr int TM = 64, TN = 64, TK = 16;
    __shared__ float As[TK][TM + 4];
    __shared__ float Bs[TK][TN + 4];
    const int tid = threadIdx.x;
    const int n0 = blockIdx.x * TN;
    const int m0 = blockIdx.y * TM;
    const int r = tid >> 2;
    const int c = tid & 3;
    const int tx = tid & 15;
    const int ty = tid >> 4;

    const int m = m0 + r;
    const float* Arow;
    if (mode == 0)      Arow = Abase + (size_t)toks0[m] * H;
    else if (mode == 1) Arow = Abase + (size_t)(m == 0 ? 0 : toks1[m - 1]) * H;
    else                Arow = Abase + (size_t)m * H;
    const float* Brow = W + (size_t)(n0 + r) * H;

    float acc[4][4] = {};

    for (int k0 = 0; k0 < H; k0 += TK) {
        float4 av = *(const float4*)(Arow + k0 + c * 4);
        float4 bv = *(const float4*)(Brow + k0 + c * 4);
        __syncthreads();
        As[c * 4 + 0][r] = av.x; As[c * 4 + 1][r] = av.y;
        As[c * 4 + 2][r] = av.z; As[c * 4 + 3][r] = av.w;
        Bs[c * 4 + 0][r] = bv.x; Bs[c * 4 + 1][r] = bv.y;
        Bs[c * 4 + 2][r] = bv.z; Bs[c * 4 + 3][r] = bv.w;
        __syncthreads();
#pragma unroll
        for (int kk = 0; kk < TK; ++kk) {
            float4 a = *(const float4*)&As[kk][ty * 4];
            float4 b = *(const float4*)&Bs[kk][tx * 4];
            float avv[4] = {a.x, a.y, a.z, a.w};
            float bvv[4] = {b.x, b.y, b.z, b.w};
#pragma unroll
            for (int i = 0; i < 4; ++i)
#pragma unroll
                for (int j = 0; j < 4; ++j)
                    acc[i][j] += avv[i] * bvv[j];
        }
    }

    float4 bq = *(const float4*)(bias + n0 + tx * 4);
    float bb[4] = {bq.x, bq.y, bq.z, bq.w};
#pragma unroll
    for (int i = 0; i < 4; ++i) {
        float4 o;
        o.x = acc[i][0] + bb[0];
        o.y = acc[i][1] + bb[1];
        o.z = acc[i][2] + bb[2];
        o.w = acc[i][3] + bb[3];
        *(float4*)&C[(size_t)(m0 + ty * 4 + i) * N + n0 + tx * 4] = o;
    }
}

extern "C" void kernel_launch(void* const* d_in, const int* in_sizes, int n_in,
                              void* d_out, int out_size, void* d_ws, size_t ws_size,
                              hipStream_t stream) {
    const int*   inputs  = (const int*)d_in[0];
    const int*   targets = (const int*)d_in[1];
    const float* emb     = (const float*)d_in[2];
    const float* eWih    = (const float*)d_in[3];
    const float* eWhh    = (const float*)d_in[4];
    const float* ebih    = (const float*)d_in[5];
    const float* ebhh    = (const float*)d_in[6];
    const float* dWih    = (const float*)d_in[7];
    const float* dWhh    = (const float*)d_in[8];
    const float* dbih    = (const float*)d_in[9];
    const float* dbhh    = (const float*)d_in[10];
    const float* pW      = (const float*)d_in[11];
    const float* pb      = (const float*)d_in[12];
    float* out = (float*)d_out;

    float* gxe    = (float*)d_ws;                  // [512][3072]
    float* gxd    = gxe + (size_t)SEQ * THREEH;    // [512][3072]
    float* dec_hs = gxd + (size_t)SEQ * THREEH;    // [512][1024]
    float* hbuf   = dec_hs + (size_t)SEQ * H;      // [2][1024]
    unsigned* flags = (unsigned*)(hbuf + 2 * H);   // [64*16]

    hipMemsetAsync(flags, 0, NBLK * 16 * sizeof(unsigned), stream);

    // input-side GEMMs: gx = Wih @ emb[tok] + bih
    gemm_nt<<<dim3(THREEH / 64, SEQ / 64), 256, 0, stream>>>(
        emb, inputs, targets, 0, eWih, ebih, gxe, THREEH);
    gemm_nt<<<dim3(THREEH / 64, SEQ / 64), 256, 0, stream>>>(
        emb, inputs, targets, 1, dWih, dbih, gxd, THREEH);

    // sequential recurrence (enc 512 steps then dec 512 steps)
    rnn_persistent<<<NBLK, 256, 0, stream>>>(
        eWhh, ebhh, dWhh, dbhh, gxe, gxd, hbuf, dec_hs, flags);

    // projection: logits = dec_hs @ proj_W^T + proj_b
    gemm_nt<<<dim3(VOCABN / 64, SEQ / 64), 256, 0, stream>>>(
        dec_hs, nullptr, nullptr, 2, pW, pb, out, VOCABN);
}